// Round 12
// baseline (62.332 us; speedup 1.0000x reference)
//
#include <hip/hip_runtime.h>
#include <stdint.h>

#define AS_G __attribute__((address_space(1)))
#define AS_L __attribute__((address_space(3)))

typedef __bf16 bf16x8 __attribute__((ext_vector_type(8)));
typedef float  f32x4  __attribute__((ext_vector_type(4)));

static constexpr int NIMG = 16, CIN = 128, H = 64, W = 64, OCH = 128;
static constexpr int HO = 62, WO = 62;
static constexpr int PIX = HO * WO;            // 3844
static constexpr int M_TOT = NIMG * PIX;       // 61504
static constexpr int K_TOT = CIN * 9;          // 1152
static constexpr int MBLK = 512;               // 8 waves x 64 m
static constexpr int NMB = (M_TOT + MBLK - 1) / MBLK;   // 121
static constexpr int NWG = NMB * 2;            // x2 o-halves = 242 blocks
static constexpr int LDS_BYTES = 64 * K_TOT * 2;        // 144 KB weight image

__device__ __forceinline__ unsigned short f2bf(float f) {
    union { float f; uint32_t u; } v; v.f = f;
    uint32_t u = v.u;
    return (unsigned short)((u + 0x7FFFu + ((u >> 16) & 1u)) >> 16);
}

// Fused prep: blocks [0,1024): NCHW fp32 -> NHWC bf16; rest: weight prep.
__global__ __launch_bounds__(256) void prep_kernel(const float* __restrict__ x,
                                                   const float* __restrict__ wsrc,
                                                   unsigned short* __restrict__ xt,
                                                   unsigned short* __restrict__ bpd) {
    __shared__ float lds[CIN][W + 4];
    if (blockIdx.x < NIMG * H) {
        const int n   = blockIdx.x >> 6;
        const int h   = blockIdx.x & 63;
        const int tid = threadIdx.x;
        {
            const int c  = tid >> 1;
            const int w0 = (tid & 1) * 32;
            const float* src = x + (((size_t)(n * CIN + c) * H + h) * W + w0);
            #pragma unroll
            for (int j = 0; j < 8; ++j) {
                float4 v = *reinterpret_cast<const float4*>(src + j * 4);
                *reinterpret_cast<float4*>(&lds[c][w0 + j * 4]) = v;
            }
        }
        __syncthreads();
        {
            const int w  = tid >> 2;
            const int c0 = (tid & 3) * 32;
            unsigned short* dst = xt + (((size_t)(n * H + h) * W + w) * CIN + c0);
            uint32_t pk[16];
            #pragma unroll
            for (int j = 0; j < 16; ++j) {
                uint32_t lo = f2bf(lds[c0 + 2 * j][w]);
                uint32_t hi = f2bf(lds[c0 + 2 * j + 1][w]);
                pk[j] = lo | (hi << 16);
            }
            #pragma unroll
            for (int j = 0; j < 4; ++j) {
                *reinterpret_cast<uint4*>(dst + j * 8) =
                    make_uint4(pk[4 * j], pk[4 * j + 1], pk[4 * j + 2], pk[4 * j + 3]);
            }
        }
    } else {
        int tid = (blockIdx.x - NIMG * H) * 256 + threadIdx.x;
        if (tid < OCH * K_TOT) {
            int o  = tid / K_TOT;
            int kp = tid - o * K_TOT;   // kp = t*128 + c
            int t  = kp >> 7;
            int c  = kp & 127;
            bpd[tid] = f2bf(wsrc[o * K_TOT + c * 9 + t]);
        }
    }
}

// Barrier-free implicit-GEMM conv, v2 (fixes R10's defects):
// 512 thr / 8 waves (2 per SIMD), wave = 64m x 64o (acc 64 VGPR).
// Weights 64o x 1152k resident in LDS (144 KB, staged once, ONE barrier).
// Main loop: 36 flattened (tap,ks) steps; 3-slot rotating depth-2 prefetch
// (4 ds_read_b128 + 4 global dwordx4 issued 2 steps ahead of their 16 MFMA).
// mfma(bfr, af, acc): D rows = o, D cols = m -> coalesced stores.
__global__ __launch_bounds__(512, 2) void gemm_kernel(const unsigned short* __restrict__ xt,
                                                      const unsigned short* __restrict__ bp,
                                                      const float* __restrict__ bias,
                                                      float* __restrict__ out) {
    extern __shared__ char lds[];
    const int tid  = threadIdx.x;
    const int wv   = tid >> 6;
    const int lane = tid & 63;
    const int lr   = lane & 15, lq = lane >> 4;

    // ---- bijective XCD swizzle (242 = 8*30+2: q=30, r=2); wg = mblk*2+oh so
    // the two o-halves sharing an A-slice land in the same XCD chunk ----
    const int orig = blockIdx.x;
    const int xcd  = orig & 7;
    const int idx  = orig >> 3;
    const int wg   = (xcd < 2 ? xcd * 31 : 62 + (xcd - 2) * 30) + idx;
    const int mblk = wg >> 1;            // 0..120
    const int oh   = wg & 1;             // o-half: [oh*64, oh*64+64)

    // ---- one-shot weight staging: 64 o x 1152 k' bf16, rows 2304 B.
    // Logical col-byte L at phys L ^ ((o&7)<<4); linear LDS dest + pre-swizzled
    // per-lane global source (verified R10: absmax 0.0156) ----
    {
        const unsigned short* wbase = bp + oh * 64 * K_TOT;
        #pragma unroll
        for (int p = 0; p < 18; ++p) {
            int s  = p * 512 + tid;              // 16B slot, 9216 total
            int o  = s / 144;                    // 144 slots per o-row
            int q  = s - o * 144;
            int Lx = (q * 16) ^ ((o & 7) << 4);  // pre-swizzled source col-byte
            __builtin_amdgcn_global_load_lds(
                (AS_G unsigned int*)(wbase + o * K_TOT + (Lx >> 1)),
                (AS_L unsigned int*)(lds + p * 8192 + wv * 1024),   // uniform base
                16, 0, 0);
        }
    }

    // ---- per-wave m geometry (wave owns 64 m) ----
    int pixBase[4], obase[4];
    bool valid[4];
    #pragma unroll
    for (int mi = 0; mi < 4; ++mi) {
        int m = mblk * MBLK + wv * 64 + mi * 16 + lr;
        valid[mi] = (m < M_TOT);
        if (m >= M_TOT) m = M_TOT - 1;
        int n  = m / PIX;
        int r  = m - n * PIX;
        int y  = r / WO;
        int xx = r - y * WO;
        pixBase[mi] = ((n * H + y) * W + xx) * CIN;     // NHWC elems, tap(0,0)
        obase[mi]   = n * OCH * PIX + y * WO + xx;      // out elems, o=0
    }

    // bfr read geometry: o-row = ni*16+lr (rows 2304 B); within-row logical
    // col-byte = t*256 + ks*64 + lq*16, phys XOR ((lr&7)<<4) on low bits
    int bRow[4];
    #pragma unroll
    for (int ni = 0; ni < 4; ++ni)
        bRow[ni] = (ni * 16 + lr) * 2304;
    int colk[4];
    #pragma unroll
    for (int ks = 0; ks < 4; ++ks)
        colk[ks] = (ks * 64 + lq * 16) ^ ((lr & 7) << 4);
    const int kfrag = lq * 8;                           // elems

    f32x4 acc[4][4];
    #pragma unroll
    for (int a = 0; a < 4; ++a)
        #pragma unroll
        for (int b = 0; b < 4; ++b)
            acc[a][b] = (f32x4){0.f, 0.f, 0.f, 0.f};

    // wait for the weight image, once (drains vmcnt + barrier)
    __syncthreads();

    // ---- main loop: 36 steps (t = s>>2, ks = s&3), depth-2 rotating prefetch,
    // NO barriers: waves free-run ----
    bf16x8 afb[3][4];   // [slot][mi]
    bf16x8 bfb[3][4];   // [slot][ni]
    auto issue = [&](int s) {
        const int slot = s % 3;
        const int t = s >> 2, ks = s & 3;
        const int tapoff = (t / 3) * (W * CIN) + (t % 3) * CIN + ks * 32;  // elems
        #pragma unroll
        for (int mi = 0; mi < 4; ++mi)
            afb[slot][mi] = *(const bf16x8*)(xt + pixBase[mi] + tapoff + kfrag);
        #pragma unroll
        for (int ni = 0; ni < 4; ++ni)
            bfb[slot][ni] = *(const bf16x8*)(lds + bRow[ni] + t * 256 + colk[ks]);
    };

    issue(0);
    issue(1);
    #pragma unroll
    for (int s = 0; s < 36; ++s) {
        if (s + 2 < 36) issue(s + 2);
        const int slot = s % 3;
        #pragma unroll
        for (int mi = 0; mi < 4; ++mi)
            #pragma unroll
            for (int ni = 0; ni < 4; ++ni)
                acc[mi][ni] = __builtin_amdgcn_mfma_f32_16x16x32_bf16(
                    bfb[slot][ni], afb[slot][mi], acc[mi][ni], 0, 0, 0);
    }

    // ---- epilogue: D col = lane&15 = m (consecutive x), row = lq*4+j = o ----
    f32x4 bv[4];
    #pragma unroll
    for (int ni = 0; ni < 4; ++ni)
        bv[ni] = *(const f32x4*)(bias + oh * 64 + ni * 16 + lq * 4);
    #pragma unroll
    for (int mi = 0; mi < 4; ++mi) {
        if (valid[mi]) {
            float* ob = out + obase[mi];
            #pragma unroll
            for (int ni = 0; ni < 4; ++ni) {
                const int o = oh * 64 + ni * 16 + lq * 4;
                #pragma unroll
                for (int j = 0; j < 4; ++j)
                    ob[(size_t)(o + j) * PIX] = acc[mi][ni][j] + bv[ni][j];
            }
        }
    }
}

extern "C" void kernel_launch(void* const* d_in, const int* in_sizes, int n_in,
                              void* d_out, int out_size, void* d_ws, size_t ws_size,
                              hipStream_t stream) {
    const float* x    = (const float*)d_in[0];
    const float* wsrc = (const float*)d_in[1];
    const float* bias = (const float*)d_in[2];
    float* out = (float*)d_out;
    unsigned short* xt = (unsigned short*)d_ws;                 // 16 MiB NHWC bf16
    unsigned short* bp = xt + (size_t)NIMG * H * W * CIN;       // 288 KiB weights
    prep_kernel<<<dim3(NIMG * H + (OCH * K_TOT + 255) / 256), dim3(256), 0, stream>>>(
        x, wsrc, xt, bp);
    gemm_kernel<<<dim3(NWG), dim3(512), LDS_BYTES, stream>>>(xt, bp, bias, out);
}

// Round 13
// 46.920 us; speedup vs baseline: 1.3285x; 1.3285x over previous
//
#include <hip/hip_runtime.h>
#include <stdint.h>

#define AS_G __attribute__((address_space(1)))
#define AS_L __attribute__((address_space(3)))

typedef __bf16 bf16x8 __attribute__((ext_vector_type(8)));
typedef float  f32x4  __attribute__((ext_vector_type(4)));

static constexpr int NIMG = 16, CIN = 128, H = 64, W = 64, OCH = 128;
static constexpr int HO = 62, WO = 62;
static constexpr int PIX = HO * WO;            // 3844
static constexpr int M_TOT = NIMG * PIX;       // 61504
static constexpr int K_TOT = CIN * 9;          // 1152
static constexpr int BM = 64, BN = 64, BK = 64;
static constexpr int KSTEPS = K_TOT / BK;      // 18
static constexpr int NWG = (M_TOT / BM) * 2;   // 1922 blocks (7.5/CU)

__device__ __forceinline__ unsigned short f2bf(float f) {
    union { float f; uint32_t u; } v; v.f = f;
    uint32_t u = v.u;
    return (unsigned short)((u + 0x7FFFu + ((u >> 16) & 1u)) >> 16);
}

// Fused prep: blocks [0,1024): NCHW fp32 -> NHWC bf16; rest: weight prep.
__global__ __launch_bounds__(256) void prep_kernel(const float* __restrict__ x,
                                                   const float* __restrict__ wsrc,
                                                   unsigned short* __restrict__ xt,
                                                   unsigned short* __restrict__ bpd) {
    __shared__ float lds[CIN][W + 4];
    if (blockIdx.x < NIMG * H) {
        const int n   = blockIdx.x >> 6;
        const int h   = blockIdx.x & 63;
        const int tid = threadIdx.x;
        {
            const int c  = tid >> 1;
            const int w0 = (tid & 1) * 32;
            const float* src = x + (((size_t)(n * CIN + c) * H + h) * W + w0);
            #pragma unroll
            for (int j = 0; j < 8; ++j) {
                float4 v = *reinterpret_cast<const float4*>(src + j * 4);
                *reinterpret_cast<float4*>(&lds[c][w0 + j * 4]) = v;
            }
        }
        __syncthreads();
        {
            const int w  = tid >> 2;
            const int c0 = (tid & 3) * 32;
            unsigned short* dst = xt + (((size_t)(n * H + h) * W + w) * CIN + c0);
            uint32_t pk[16];
            #pragma unroll
            for (int j = 0; j < 16; ++j) {
                uint32_t lo = f2bf(lds[c0 + 2 * j][w]);
                uint32_t hi = f2bf(lds[c0 + 2 * j + 1][w]);
                pk[j] = lo | (hi << 16);
            }
            #pragma unroll
            for (int j = 0; j < 4; ++j) {
                *reinterpret_cast<uint4*>(dst + j * 8) =
                    make_uint4(pk[4 * j], pk[4 * j + 1], pk[4 * j + 2], pk[4 * j + 3]);
            }
        }
    } else {
        int tid = (blockIdx.x - NIMG * H) * 256 + threadIdx.x;
        if (tid < OCH * K_TOT) {
            int o  = tid / K_TOT;
            int kp = tid - o * K_TOT;   // kp = t*128 + c
            int t  = kp >> 7;
            int c  = kp & 127;
            bpd[tid] = f2bf(wsrc[o * K_TOT + c * 9 + t]);
        }
    }
}

// Implicit-GEMM conv: C[m][o] = sum_k A[m][k]*W[o][k], m=(n,y,x), k=(t,c)
// TLP round: 64x64 output tile -> 1922 blocks (7.5/CU), 16 KB LDS, ~55 VGPR
// -> many co-resident blocks interleave their staging drains.
// 2-barrier K-loop (best-measured), 0-conflict XOR staging, bijective XCD
// swizzle, swapped-operand MFMA (D rows = o, cols = m -> coalesced stores).
__global__ __launch_bounds__(256) void gemm_kernel(const unsigned short* __restrict__ xt,
                                                   const unsigned short* __restrict__ bp,
                                                   const float* __restrict__ bias,
                                                   float* __restrict__ out) {
    __shared__ alignas(16) unsigned short As[BM * BK];   // 8 KB, XOR-swizzled
    __shared__ alignas(16) unsigned short Bs[BN * BK];   // 8 KB, XOR-swizzled
    const int tid  = threadIdx.x;
    const int wv   = tid >> 6;
    const int lane = tid & 63;

    // ---- bijective XCD swizzle (1922 = 8*240+2: q=240, r=2) ----
    const int orig = blockIdx.x;
    const int xcd  = orig & 7;
    const int idx  = orig >> 3;
    const int wg   = (xcd < 2 ? xcd * 241 : 482 + (xcd - 2) * 240) + idx;
    const int mblk = wg >> 1;            // 0..960
    const int oh   = wg & 1;             // o-half: [oh*64, oh*64+64)
    const int m0   = mblk * BM;          // 961*64 == M_TOT: no m bounds checks
    const int o0   = oh * 64;

    // staging: slot s covers bytes [s*16,s*16+16); row = s>>3 (8 slots / 128B row)
    // phys_byte = row*128 + (colbyte ^ ((row&7)<<4)); row&7 == (lane>>3)&7:
    const int csel = ((lane & 7) ^ (lane >> 3)) * 8;   // source col offset, elems
    int aBase[2], bBase[2];
    #pragma unroll
    for (int i = 0; i < 2; ++i) {
        int row = i * 32 + (tid >> 3);                 // m-row 0..63
        int m = m0 + row;
        int n  = m / PIX;
        int r  = m - n * PIX;
        int y  = r / WO;
        int xx = r - y * WO;
        aBase[i] = ((n * H + y) * W + xx) * CIN;       // NHWC elem index, tap 0
        bBase[i] = (o0 + row) * K_TOT;                 // o-row
    }
    // per-wave uniform LDS dest bases: s = i*256 + wv*64 + lane
    // dst = base + (i*256 + wv*64)*16 + lane*16

    // compute-side fragment addresses: wave tile 32m x 32o (2x2 wave grid)
    const int wr = wv >> 1, wc = wv & 1;
    const int lr = lane & 15, lq = lane >> 4;
    const int aRow = (wr * 32 + lr) * 128;             // byte offset of m-row
    const int bRow = (wc * 32 + lr) * 128;             // byte offset of o-row
    int colx[2];
    #pragma unroll
    for (int ks = 0; ks < 2; ++ks)
        colx[ks] = (ks * 64 + lq * 16) ^ ((lane & 7) << 4);

    f32x4 acc[2][2];
    #pragma unroll
    for (int a = 0; a < 2; ++a)
        #pragma unroll
        for (int b = 0; b < 2; ++b)
            acc[a][b] = (f32x4){0.f, 0.f, 0.f, 0.f};

    const char* AsB = (const char*)As;
    const char* BsB = (const char*)Bs;

    for (int step = 0; step < KSTEPS; ++step) {
        const int t  = step >> 1;
        const int c0 = (step & 1) * 64;
        const int tapoff = (t / 3) * (W * CIN) + (t % 3) * CIN + c0;
        const int kb = step * BK;
        #pragma unroll
        for (int i = 0; i < 2; ++i) {
            __builtin_amdgcn_global_load_lds(
                (AS_G unsigned int*)(xt + aBase[i] + tapoff + csel),
                (AS_L unsigned int*)((char*)As + i * 4096 + wv * 1024),
                16, 0, 0);
            __builtin_amdgcn_global_load_lds(
                (AS_G unsigned int*)(bp + bBase[i] + kb + csel),
                (AS_L unsigned int*)((char*)Bs + i * 4096 + wv * 1024),
                16, 0, 0);
        }
        __syncthreads();   // drains vmcnt (compiler) + rendezvous
        #pragma unroll
        for (int ks = 0; ks < 2; ++ks) {
            bf16x8 af[2], bfr[2];
            #pragma unroll
            for (int mi = 0; mi < 2; ++mi)
                af[mi] = *(const bf16x8*)(AsB + aRow + mi * 2048 + colx[ks]);
            #pragma unroll
            for (int ni = 0; ni < 2; ++ni)
                bfr[ni] = *(const bf16x8*)(BsB + bRow + ni * 2048 + colx[ks]);
            #pragma unroll
            for (int mi = 0; mi < 2; ++mi)
                #pragma unroll
                for (int ni = 0; ni < 2; ++ni)
                    acc[mi][ni] = __builtin_amdgcn_mfma_f32_16x16x32_bf16(
                        bfr[ni], af[mi], acc[mi][ni], 0, 0, 0);   // D rows=o, cols=m
        }
        __syncthreads();
    }

    // epilogue: D col = lane&15 = m (consecutive!), row = (lane>>4)*4+j = o
    f32x4 bv[2];
    #pragma unroll
    for (int ni = 0; ni < 2; ++ni)
        bv[ni] = *(const f32x4*)(bias + o0 + wc * 32 + ni * 16 + lq * 4);
    #pragma unroll
    for (int mi = 0; mi < 2; ++mi) {
        int m = m0 + wr * 32 + mi * 16 + lr;
        int n  = m / PIX;
        int r  = m - n * PIX;
        int y  = r / WO;
        int xx = r - y * WO;
        float* ob = out + (size_t)n * OCH * PIX + y * WO + xx;
        #pragma unroll
        for (int ni = 0; ni < 2; ++ni)
            #pragma unroll
            for (int j = 0; j < 4; ++j) {
                int o = o0 + wc * 32 + ni * 16 + lq * 4 + j;
                ob[(size_t)o * PIX] = acc[mi][ni][j] + bv[ni][j];
            }
    }
}

extern "C" void kernel_launch(void* const* d_in, const int* in_sizes, int n_in,
                              void* d_out, int out_size, void* d_ws, size_t ws_size,
                              hipStream_t stream) {
    const float* x    = (const float*)d_in[0];
    const float* wsrc = (const float*)d_in[1];
    const float* bias = (const float*)d_in[2];
    float* out = (float*)d_out;
    unsigned short* xt = (unsigned short*)d_ws;                 // 16 MiB NHWC bf16
    unsigned short* bp = xt + (size_t)NIMG * H * W * CIN;       // 288 KiB weights
    prep_kernel<<<dim3(NIMG * H + (OCH * K_TOT + 255) / 256), dim3(256), 0, stream>>>(
        x, wsrc, xt, bp);
    gemm_kernel<<<dim3(NWG), dim3(256), 0, stream>>>(xt, bp, bias, out);
}

// Round 14
// 46.108 us; speedup vs baseline: 1.3519x; 1.0176x over previous
//
#include <hip/hip_runtime.h>
#include <stdint.h>

#define AS_G __attribute__((address_space(1)))
#define AS_L __attribute__((address_space(3)))

typedef __bf16 bf16x8 __attribute__((ext_vector_type(8)));
typedef float  f32x4  __attribute__((ext_vector_type(4)));

static constexpr int NIMG = 16, CIN = 128, H = 64, W = 64, OCH = 128;
static constexpr int HO = 62, WO = 62;
static constexpr int PIX = HO * WO;            // 3844
static constexpr int M_TOT = NIMG * PIX;       // 61504
static constexpr int K_TOT = CIN * 9;          // 1152
static constexpr int BM = 256, BK = 64;
static constexpr int NT = K_TOT / BK;          // 18 K-tiles
static constexpr int NWG = (M_TOT + BM - 1) / BM;   // 241
static constexpr int ASZ = BM * BK * 2;        // 32 KB
static constexpr int BSZ = OCH * BK * 2;       // 16 KB
static constexpr int SLOT = ASZ + BSZ;         // 48 KB
static constexpr int LDS_BYTES = 3 * SLOT;     // 144 KB ring

__device__ __forceinline__ unsigned short f2bf(float f) {
    union { float f; uint32_t u; } v; v.f = f;
    uint32_t u = v.u;
    return (unsigned short)((u + 0x7FFFu + ((u >> 16) & 1u)) >> 16);
}

// Fused prep: blocks [0,1024): NCHW fp32 -> NHWC bf16; rest: weight prep.
__global__ __launch_bounds__(256) void prep_kernel(const float* __restrict__ x,
                                                   const float* __restrict__ wsrc,
                                                   unsigned short* __restrict__ xt,
                                                   unsigned short* __restrict__ bpd) {
    __shared__ float lds[CIN][W + 4];
    if (blockIdx.x < NIMG * H) {
        const int n   = blockIdx.x >> 6;
        const int h   = blockIdx.x & 63;
        const int tid = threadIdx.x;
        {
            const int c  = tid >> 1;
            const int w0 = (tid & 1) * 32;
            const float* src = x + (((size_t)(n * CIN + c) * H + h) * W + w0);
            #pragma unroll
            for (int j = 0; j < 8; ++j) {
                float4 v = *reinterpret_cast<const float4*>(src + j * 4);
                *reinterpret_cast<float4*>(&lds[c][w0 + j * 4]) = v;
            }
        }
        __syncthreads();
        {
            const int w  = tid >> 2;
            const int c0 = (tid & 3) * 32;
            unsigned short* dst = xt + (((size_t)(n * H + h) * W + w) * CIN + c0);
            uint32_t pk[16];
            #pragma unroll
            for (int j = 0; j < 16; ++j) {
                uint32_t lo = f2bf(lds[c0 + 2 * j][w]);
                uint32_t hi = f2bf(lds[c0 + 2 * j + 1][w]);
                pk[j] = lo | (hi << 16);
            }
            #pragma unroll
            for (int j = 0; j < 4; ++j) {
                *reinterpret_cast<uint4*>(dst + j * 8) =
                    make_uint4(pk[4 * j], pk[4 * j + 1], pk[4 * j + 2], pk[4 * j + 3]);
            }
        }
    } else {
        int tid = (blockIdx.x - NIMG * H) * 256 + threadIdx.x;
        if (tid < OCH * K_TOT) {
            int o  = tid / K_TOT;
            int kp = tid - o * K_TOT;   // kp = t*128 + c
            int t  = kp >> 7;
            int c  = kp & 127;
            bpd[tid] = f2bf(wsrc[o * K_TOT + c * 9 + t]);
        }
    }
}

// Implicit-GEMM conv, faithful 8-phase-template port (fine interleave):
// BM=256 x BN=128, BK=64, 8 waves (64x64 each), ring-3 LDS. Per K-tile two
// phases: {8 ds_read ; 3 stage-issue ; barrier ; lgkmcnt(0) ; setprio(1) ;
// 16 MFMA ; setprio(0) ; barrier}. vmcnt(6) ONCE per K-tile, placed before
// the phase-2 barrier so the barrier publishes all waves' counted waits.
// mfma(bfr, af, acc): D rows = o, D cols = m -> coalesced stores.
__global__ __launch_bounds__(512, 1) void gemm_kernel(const unsigned short* __restrict__ xt,
                                                      const unsigned short* __restrict__ bp,
                                                      const float* __restrict__ bias,
                                                      float* __restrict__ out) {
    extern __shared__ char lds[];
    const int tid  = threadIdx.x;
    const int wv   = tid >> 6;          // 0..7
    const int lane = tid & 63;

    // ---- bijective XCD swizzle (241 = 8*30+1: q=30, r=1) ----
    const int orig = blockIdx.x;
    const int xcd  = orig & 7;
    const int idx  = orig >> 3;
    const int wg   = (xcd == 0 ? 0 : 31 + (xcd - 1) * 30) + idx;
    const int m0   = wg * BM;

    // staging geometry (R8-verified): slot s covers phys [s*16, s*16+16);
    // row = s>>3; phys = row*128 + (col ^ ((row&7)<<4)); row&7 == (tid>>3)&7:
    const int csel = ((tid & 7) ^ ((tid >> 3) & 7)) * 8;   // src col offset, elems
    int aBase[4];
    #pragma unroll
    for (int p = 0; p < 4; ++p) {
        int row = p * 64 + (tid >> 3);                     // m-row 0..255
        int m = m0 + row; if (m >= M_TOT) m = M_TOT - 1;   // clamp; store-masked
        int n  = m / PIX;
        int r  = m - n * PIX;
        int y  = r / WO;
        int xx = r - y * WO;
        aBase[p] = ((n * H + y) * W + xx) * CIN;           // NHWC elems, tap 0
    }
    int bBase[2];
    #pragma unroll
    for (int p = 0; p < 2; ++p)
        bBase[p] = (p * 64 + (tid >> 3)) * K_TOT;          // o-row 0..127

    auto stA = [&](char* dst, int step, int p) {
        const int tt = step >> 1, c0 = (step & 1) * 64;
        const int tapoff = (tt / 3) * (W * CIN) + (tt % 3) * CIN + c0;
        __builtin_amdgcn_global_load_lds(
            (AS_G unsigned int*)(xt + aBase[p] + tapoff + csel),
            (AS_L unsigned int*)(dst + p * 8192 + wv * 1024), 16, 0, 0);
    };
    auto stB = [&](char* dst, int step, int p) {
        __builtin_amdgcn_global_load_lds(
            (AS_G unsigned int*)(bp + bBase[p] + step * BK + csel),
            (AS_L unsigned int*)(dst + ASZ + p * 8192 + wv * 1024), 16, 0, 0);
    };

    // compute-side fragment addresses: wave grid 4m x 2o, tile 64x64
    const int wr = wv >> 1, wc = wv & 1;
    const int lr = lane & 15, lq = lane >> 4;
    const int aRow = (wr * 64 + lr) * 128;                 // byte off of m-row
    const int bRow = ASZ + (wc * 64 + lr) * 128;           // byte off of o-row
    int colx[2];
    #pragma unroll
    for (int ks = 0; ks < 2; ++ks)
        colx[ks] = (ks * 64 + lq * 16) ^ ((lane & 7) << 4);

    f32x4 acc[4][4];
    #pragma unroll
    for (int a = 0; a < 4; ++a)
        #pragma unroll
        for (int b = 0; b < 4; ++b)
            acc[a][b] = (f32x4){0.f, 0.f, 0.f, 0.f};

    // ---- prologue: stage tiles 0,1 (6 loads each); wait tile 0, publish ----
    {
        char* d0 = lds;
        char* d1 = lds + SLOT;
        #pragma unroll
        for (int p = 0; p < 4; ++p) stA(d0, 0, p);
        stB(d0, 0, 0); stB(d0, 0, 1);
        #pragma unroll
        for (int p = 0; p < 4; ++p) stA(d1, 1, p);
        stB(d1, 1, 0); stB(d1, 1, 1);
        asm volatile("s_waitcnt vmcnt(6)" ::: "memory");   // tile 0 done, 1 in flight
        __builtin_amdgcn_s_barrier();
        __builtin_amdgcn_sched_barrier(0);
    }

    for (int t = 0; t < NT; ++t) {
        const char* cur = lds + (t % 3) * SLOT;
        char* nxt = lds + ((t + 2) % 3) * SLOT;
        const bool doStage = (t + 2 < NT);
        const int st = t + 2;
        // ---------- phase 1: ks = 0 ----------
        {
            bf16x8 af[4], bfr[4];
            #pragma unroll
            for (int mi = 0; mi < 4; ++mi)
                af[mi] = *(const bf16x8*)(cur + aRow + mi * 2048 + colx[0]);
            #pragma unroll
            for (int ni = 0; ni < 4; ++ni)
                bfr[ni] = *(const bf16x8*)(cur + bRow + ni * 2048 + colx[0]);
            if (doStage) { stA(nxt, st, 0); stA(nxt, st, 1); stA(nxt, st, 2); }
            __builtin_amdgcn_s_barrier();
            asm volatile("s_waitcnt lgkmcnt(0)" ::: "memory");
            __builtin_amdgcn_sched_barrier(0);
            __builtin_amdgcn_s_setprio(1);
            #pragma unroll
            for (int mi = 0; mi < 4; ++mi)
                #pragma unroll
                for (int ni = 0; ni < 4; ++ni)
                    acc[mi][ni] = __builtin_amdgcn_mfma_f32_16x16x32_bf16(
                        bfr[ni], af[mi], acc[mi][ni], 0, 0, 0);
            __builtin_amdgcn_s_setprio(0);
            __builtin_amdgcn_s_barrier();
        }
        // ---------- phase 2: ks = 1 ----------
        {
            bf16x8 af[4], bfr[4];
            #pragma unroll
            for (int mi = 0; mi < 4; ++mi)
                af[mi] = *(const bf16x8*)(cur + aRow + mi * 2048 + colx[1]);
            #pragma unroll
            for (int ni = 0; ni < 4; ++ni)
                bfr[ni] = *(const bf16x8*)(cur + bRow + ni * 2048 + colx[1]);
            if (doStage) { stA(nxt, st, 3); stB(nxt, st, 0); stB(nxt, st, 1); }
            __builtin_amdgcn_s_barrier();
            asm volatile("s_waitcnt lgkmcnt(0)" ::: "memory");
            __builtin_amdgcn_sched_barrier(0);
            __builtin_amdgcn_s_setprio(1);
            #pragma unroll
            for (int mi = 0; mi < 4; ++mi)
                #pragma unroll
                for (int ni = 0; ni < 4; ++ni)
                    acc[mi][ni] = __builtin_amdgcn_mfma_f32_16x16x32_bf16(
                        bfr[ni], af[mi], acc[mi][ni], 0, 0, 0);
            __builtin_amdgcn_s_setprio(0);
            // counted wait for buf t+1 BEFORE the publishing barrier
            if (t < NT - 2)      asm volatile("s_waitcnt vmcnt(6)" ::: "memory");
            else if (t < NT - 1) asm volatile("s_waitcnt vmcnt(0)" ::: "memory");
            __builtin_amdgcn_s_barrier();
            __builtin_amdgcn_sched_barrier(0);
        }
    }

    // ---- epilogue: D col = lane&15 = m (consecutive x), row = lq*4+j = o ----
    f32x4 bv[4];
    #pragma unroll
    for (int ni = 0; ni < 4; ++ni)
        bv[ni] = *(const f32x4*)(bias + wc * 64 + ni * 16 + lq * 4);
    #pragma unroll
    for (int mi = 0; mi < 4; ++mi) {
        int m = m0 + wr * 64 + mi * 16 + lr;
        if (m < M_TOT) {
            int n  = m / PIX;
            int r  = m - n * PIX;
            int y  = r / WO;
            int xx = r - y * WO;
            float* ob = out + (size_t)n * OCH * PIX + y * WO + xx;
            #pragma unroll
            for (int ni = 0; ni < 4; ++ni)
                #pragma unroll
                for (int j = 0; j < 4; ++j) {
                    int o = wc * 64 + ni * 16 + lq * 4 + j;
                    ob[(size_t)o * PIX] = acc[mi][ni][j] + bv[ni][j];
                }
        }
    }
}

extern "C" void kernel_launch(void* const* d_in, const int* in_sizes, int n_in,
                              void* d_out, int out_size, void* d_ws, size_t ws_size,
                              hipStream_t stream) {
    const float* x    = (const float*)d_in[0];
    const float* wsrc = (const float*)d_in[1];
    const float* bias = (const float*)d_in[2];
    float* out = (float*)d_out;
    unsigned short* xt = (unsigned short*)d_ws;                 // 16 MiB NHWC bf16
    unsigned short* bp = xt + (size_t)NIMG * H * W * CIN;       // 288 KiB weights
    prep_kernel<<<dim3(NIMG * H + (OCH * K_TOT + 255) / 256), dim3(256), 0, stream>>>(
        x, wsrc, xt, bp);
    gemm_kernel<<<dim3(NWG), dim3(512), LDS_BYTES, stream>>>(xt, bp, bias, out);
}